// Round 1
// 173.126 us; speedup vs baseline: 1.2162x; 1.2162x over previous
//
#include <hip/hip_runtime.h>

// Circuit_67473936220746, round 6: one block per h (512 x 1024 threads),
// state tile staged ONCE into LDS pre-split bf16 h/l in frag-linear layout
// (XOR-swizzled slots), then pass A (LDS A-frags x global WA), MID overwrites
// the state LDS region, pass B (LDS MID x global WB). 3 barriers.
//
// State per high-index h (bits 14-22): T[ch][b][a] (b = bits 7-13, a = bits 0-6).
//   Pass A: mid[kp=ch'*128+ka][b] = sum_{ch,a} WA[kp][ch*128+a] * T[ch][b][a]
//   Pass B: out[ch''][kb][ka]     = sum_{ch',b} WB[ch''*128+kb][ch'*128+b] * mid[ch'*128+ka][b]
// WA = W2*W1*W0 (fp32 on device), WB = W3, Wg = [[Ui,Ur],[Ur,-Ui]].
// 3-term bf16 split both passes (ah*bh + al*bh + ah*bl).
//
// MFMA 16x16x32 bf16 layouts (HW-verified):
//   A: m = lane&15, k = (lane>>4)*8 + j (16B/lane contiguous)
//   B: n = lane&15, k = (lane>>4)*8 + j
//   C/D: col(n) = lane&15, row(m) = (lane>>4)*4 + reg
//
// Frag-linear storage: frag(tile,ks) = 64 slots x 8 shorts; lane reads 16 B at
// frag*1024 + lane*16 (conflict-free-minimum b128). State LDS additionally
// XORs the slot's low 3 bits with (frag&7) so the a-major staging ds_write_b64
// spreads over 8 banks (16-way -> 4-way); reads XOR the same constant
// (bijection per frag => still conflict-free).

typedef __attribute__((ext_vector_type(8))) short bf16x8;
typedef __attribute__((ext_vector_type(4))) short bf16x4;
typedef __attribute__((ext_vector_type(4))) float f32x4;

static constexpr int NSTATE = 1 << 23;

// truncation split: x ~= bf16(h) + bf16(l), rel err ~2^-16
__device__ inline void tsplit(float x, unsigned short& h, unsigned short& l) {
    unsigned int u = __float_as_uint(x);
    h = (unsigned short)(u >> 16);
    float hf = __uint_as_float(u & 0xFFFF0000u);
    l = (unsigned short)(__float_as_uint(x - hf) >> 16);
}

// RNE split (weights, prep only)
__device__ inline void rsplit(float x, unsigned short& h, unsigned short& l) {
    unsigned int u = __float_as_uint(x);
    unsigned int r = (u + 0x7FFFu + ((u >> 16) & 1u)) >> 16;
    h = (unsigned short)r;
    float hf = __uint_as_float(r << 16);
    unsigned int u2 = __float_as_uint(x - hf);
    l = (unsigned short)((u2 + 0x7FFFu + ((u2 >> 16) & 1u)) >> 16);
}

// signed block-matrix element: Wg[kp][ap], Ug -> U[g][0][0][0]
__device__ inline float wElem(const float* __restrict__ Ug, int kp, int ap) {
    const int co = kp >> 7, ci = ap >> 7;
    const float v = Ug[((co == ci) ? 16384 : 0) + (kp & 127) * 128 + (ap & 127)];
    return (co & ci) ? -v : v;
}

// frag-linear scatter offset (in shorts) for element (row i, col t) of a 256x256 W
__device__ inline int fragOff(int i, int t) {
    const int frag = (i >> 4) * 8 + (t >> 5);
    const int slot = (i & 15) + 16 * ((t >> 3) & 3);
    return frag * 512 + slot * 8 + (t & 7);
}

// state-LDS frag-linear offset with slot-XOR swizzle (128 rows b x 256 cols kk)
__device__ inline int sFragOffSwz(int b, int kk) {
    const int frag = (b >> 4) * 8 + (kk >> 5);
    const int slot = ((b & 15) + 16 * ((kk >> 3) & 3)) ^ (frag & 7);
    return frag * 512 + slot * 8 + (kk & 7);
}

// ---- prep 1: blocks 0-255: T = W1*W0 (fp32); blocks 256-511: WB = W3 split ----
__global__ __launch_bounds__(256)
void prep_TWB(const float* __restrict__ U, float* __restrict__ T,
              unsigned short* __restrict__ WBh, unsigned short* __restrict__ WBl) {
    __shared__ float Arow[256];
    const int t = threadIdx.x;
    if (blockIdx.x < 256) {
        const int i = blockIdx.x;
        Arow[t] = wElem(U + 32768, i, t);               // W1 row i
        __syncthreads();
        float s = 0.f;
        #pragma unroll 8
        for (int k = 0; k < 256; ++k)
            s = fmaf(Arow[k], wElem(U, k, t), s);       // W0[k][t]
        T[i * 256 + t] = s;
    } else {
        const int i = blockIdx.x - 256;
        unsigned short h, l;
        rsplit(wElem(U + 3 * 32768, i, t), h, l);
        const int off = fragOff(i, t);
        WBh[off] = h; WBl[off] = l;
    }
}

// ---- prep 2: WA = W2*T, split + scatter to frag layout ----
__global__ __launch_bounds__(256)
void prep_WA(const float* __restrict__ U, const float* __restrict__ T,
             unsigned short* __restrict__ Wh, unsigned short* __restrict__ Wl) {
    __shared__ float Arow[256];
    const int i = blockIdx.x, t = threadIdx.x;
    Arow[t] = wElem(U + 2 * 32768, i, t);               // W2 row i
    __syncthreads();
    float s = 0.f;
    #pragma unroll 8
    for (int k = 0; k < 256; ++k)
        s = fmaf(Arow[k], T[k * 256 + t], s);
    unsigned short h, l;
    rsplit(s, h, l);
    const int off = fragOff(i, t);
    Wh[off] = h; Wl[off] = l;
}

// ---- fused main: 512 blocks (one per h) x 1024 threads (16 waves) ----
__global__ __launch_bounds__(1024, 4)
void fused3(const float* __restrict__ src, float* __restrict__ dst,
            const unsigned short* __restrict__ WAh, const unsigned short* __restrict__ WAl,
            const unsigned short* __restrict__ WBh, const unsigned short* __restrict__ WBl)
{
    // 64 KB each: state-high/low during pass A, MID-high/low during pass B
    __shared__ unsigned short Sh[32768];
    __shared__ unsigned short Sl[32768];

    const int t    = threadIdx.x;
    const int lane = t & 63;
    const int w    = t >> 6;            // 0..15
    const int col  = lane & 15, quad = lane >> 4;
    const size_t hbase = (size_t)blockIdx.x * 16384;

    // ============ STAGE: global fp32 -> split bf16 h/l -> LDS frag-linear ============
    // thread t: a4 = t&31 (float4 within a-row), r0 = t>>5 (row within 32-group);
    // iter i: ch = i>>2, b = (i&3)*32 + r0. Half-wave reads 512 B contiguous.
    {
        const int r0  = t >> 5;
        const int a4  = t & 31;
        const int kkl = a4 * 4;
        #pragma unroll
        for (int i = 0; i < 8; ++i) {
            const int ch = i >> 2;
            const int b  = (i & 3) * 32 + r0;
            const float* p = src + (size_t)ch * NSTATE + hbase + (size_t)b * 128 + kkl;
            const float4 v = *(const float4*)p;
            const int kk = ch * 128 + kkl;
            unsigned short h0, h1, h2, h3, l0, l1, l2v, l3;
            tsplit(v.x, h0, l0); tsplit(v.y, h1, l1);
            tsplit(v.z, h2, l2v); tsplit(v.w, h3, l3);
            const int off = sFragOffSwz(b, kk);     // kk&7 in {0,4}: 8B aligned
            bf16x4 hv = { (short)h0, (short)h1, (short)h2, (short)h3 };
            bf16x4 lv = { (short)l0, (short)l1, (short)l2v, (short)l3 };
            *(bf16x4*)&Sh[off] = hv;
            *(bf16x4*)&Sl[off] = lv;
        }
    }
    __syncthreads();

    // ============ PASS A ============
    // m = b: 8 tiles, wave-group mg = w>>3 owns 4; n = kp: 16 tiles, ng = w&7 owns 2.
    const int mg = w >> 3;
    const int ng = w & 7;

    f32x4 acc[4][2];
    #pragma unroll
    for (int mi = 0; mi < 4; ++mi)
        #pragma unroll
        for (int l2 = 0; l2 < 2; ++l2) acc[mi][l2] = (f32x4)0.f;

    #pragma unroll 2
    for (int ks = 0; ks < 8; ++ks) {
        bf16x8 ah[4], al[4];
        #pragma unroll
        for (int mi = 0; mi < 4; ++mi) {
            const int fr = (mg * 4 + mi) * 8 + ks;
            const int fo = fr * 512 + (lane ^ (fr & 7)) * 8;   // un-swizzle slot
            ah[mi] = *(const bf16x8*)&Sh[fo];
            al[mi] = *(const bf16x8*)&Sl[fo];
        }
        #pragma unroll
        for (int l2 = 0; l2 < 2; ++l2) {
            const int nt = ng * 2 + l2;                        // = kp>>4
            const int fo = (nt * 8 + ks) * 512 + lane * 8;
            const bf16x8 bh = *(const bf16x8*)(WAh + fo);
            const bf16x8 bl = *(const bf16x8*)(WAl + fo);
            #pragma unroll
            for (int mi = 0; mi < 4; ++mi) {
                acc[mi][l2] = __builtin_amdgcn_mfma_f32_16x16x32_bf16(ah[mi], bh, acc[mi][l2], 0, 0, 0);
                acc[mi][l2] = __builtin_amdgcn_mfma_f32_16x16x32_bf16(al[mi], bh, acc[mi][l2], 0, 0, 0);
                acc[mi][l2] = __builtin_amdgcn_mfma_f32_16x16x32_bf16(ah[mi], bl, acc[mi][l2], 0, 0, 0);
            }
        }
    }
    __syncthreads();    // all state reads complete before MID overwrites

    // ---- write MID pre-split to LDS frag layout (overwrites state region) ----
    // element (b = mt*16 + quad*4 + r, kp = nt*16 + col):
    //   ka = kp&127 -> katile = nt&7; ch' = nt>>3; k2 = ch'*128 + b
    //   frag2 = katile*8 + ch'*4 + (mt>>1); slot = col + 16*((mt*2+(quad>>1))&3);
    //   short-offset = (quad&1)*4 + r
    #pragma unroll
    for (int mi = 0; mi < 4; ++mi) {
        const int mt  = mg * 4 + mi;
        const int oct = (mt * 2 + (quad >> 1)) & 3;
        #pragma unroll
        for (int l2 = 0; l2 < 2; ++l2) {
            const int nt    = ng * 2 + l2;
            const int frag2 = (nt & 7) * 8 + (nt >> 3) * 4 + (mt >> 1);
            const int soff  = frag2 * 512 + (col + 16 * oct) * 8 + (quad & 1) * 4;
            unsigned short hh[4], ll[4];
            #pragma unroll
            for (int r = 0; r < 4; ++r) tsplit(acc[mi][l2][r], hh[r], ll[r]);
            bf16x4 hv = { (short)hh[0], (short)hh[1], (short)hh[2], (short)hh[3] };
            bf16x4 lv = { (short)ll[0], (short)ll[1], (short)ll[2], (short)ll[3] };
            *(bf16x4*)&Sh[soff] = hv;
            *(bf16x4*)&Sl[soff] = lv;
        }
    }
    __syncthreads();

    // ============ PASS B ============
    // m2 = ka: 8 tiles, mg owns 4; n2 = kp2: 16 tiles, ng owns 2.
    f32x4 acc2[4][2];
    #pragma unroll
    for (int mi = 0; mi < 4; ++mi)
        #pragma unroll
        for (int nj = 0; nj < 2; ++nj) acc2[mi][nj] = (f32x4)0.f;

    #pragma unroll 2
    for (int ks2 = 0; ks2 < 8; ++ks2) {
        bf16x8 a2h[4], a2l[4];
        #pragma unroll
        for (int mi = 0; mi < 4; ++mi) {
            const int fo = ((mg * 4 + mi) * 8 + ks2) * 512 + lane * 8;  // MID: no swizzle
            a2h[mi] = *(const bf16x8*)&Sh[fo];
            a2l[mi] = *(const bf16x8*)&Sl[fo];
        }
        #pragma unroll
        for (int nj = 0; nj < 2; ++nj) {
            const int nt2 = ng * 2 + nj;                       // = kp2>>4
            const int fo  = (nt2 * 8 + ks2) * 512 + lane * 8;
            const bf16x8 bh = *(const bf16x8*)(WBh + fo);
            const bf16x8 bl = *(const bf16x8*)(WBl + fo);
            #pragma unroll
            for (int mi = 0; mi < 4; ++mi) {
                acc2[mi][nj] = __builtin_amdgcn_mfma_f32_16x16x32_bf16(a2h[mi], bh, acc2[mi][nj], 0, 0, 0);
                acc2[mi][nj] = __builtin_amdgcn_mfma_f32_16x16x32_bf16(a2l[mi], bh, acc2[mi][nj], 0, 0, 0);
                acc2[mi][nj] = __builtin_amdgcn_mfma_f32_16x16x32_bf16(a2h[mi], bl, acc2[mi][nj], 0, 0, 0);
            }
        }
    }

    // ---- epilogue: out[ch''][kb][ka], float4 over ka (r = consecutive ka) ----
    #pragma unroll
    for (int nj = 0; nj < 2; ++nj) {
        const int kp2  = (ng * 2 + nj) * 16 + col;
        const int chpp = kp2 >> 7, kb = kp2 & 127;
        float* o = dst + (size_t)chpp * NSTATE + hbase + (size_t)kb * 128;
        #pragma unroll
        for (int mi = 0; mi < 4; ++mi) {
            const int ka = (mg * 4 + mi) * 16 + quad * 4;
            *(float4*)(o + ka) = *(float4*)&acc2[mi][nj];
        }
    }
}

extern "C" void kernel_launch(void* const* d_in, const int* in_sizes, int n_in,
                              void* d_out, int out_size, void* d_ws, size_t ws_size,
                              hipStream_t stream) {
    const float* state = (const float*)d_in[0];   // (2, 2^23)
    const float* U     = (const float*)d_in[1];   // (4, 2, 128, 128)
    float* out = (float*)d_out;

    // ws: T (256 KB fp32) | WAh WAl WBh WBl (128 KB each, frag-linear bf16)
    float* T = (float*)d_ws;
    unsigned short* WAh = (unsigned short*)(T + 65536);
    unsigned short* WAl = WAh + 65536;
    unsigned short* WBh = WAh + 2 * 65536;
    unsigned short* WBl = WAh + 3 * 65536;

    prep_TWB<<<512, 256, 0, stream>>>(U, T, WBh, WBl);
    prep_WA <<<256, 256, 0, stream>>>(U, T, WAh, WAl);
    fused3  <<<512, 1024, 0, stream>>>(state, out, WAh, WAl, WBh, WBl);
}